// Round 8
// baseline (503.330 us; speedup 1.0000x reference)
//
#include <hip/hip_runtime.h>
#include <cstdint>
#include <cstddef>

// B=2, S=2048, D=1024, H=16, HD=64. Inputs fp32, output fp32.
// R21: (1) QKV GEMM widened to 128x256 tiles (grid 12x32): same verified BK=32 core,
// B-panel doubled -> halves A-traffic and staging stores per output byte, 32 MFMA :
// 12 ds_read per K-step. Epilogues = verified two-pass pattern per n-half.
// (2) attn processes TWO q-tiles (q0, q0+64) per block sharing each K/V tile load ->
// halves KV traffic, barriers, and straggler tail. Softmax/mask/PV verbatim per tile.
// ws (40MiB): QKV[0,24M) contiguous; Xb[24,32M)->ctxb; WTall[32,38M); WoT[38,40M).
#define BB 2
#define SS 2048
#define DD 1024
#define HH 16
#define HDD 64

typedef unsigned short u16;
typedef unsigned int u32;
typedef __attribute__((ext_vector_type(8))) short bf16x8;
typedef __attribute__((ext_vector_type(4))) float f32x4;

__device__ __forceinline__ u16 f2bf(float f) {
    union { float f; u32 u; } c; c.f = f;
    u32 r = c.u + 0x7fffu + ((c.u >> 16) & 1u);  // RNE
    return (u16)(r >> 16);
}

// ---------------- prep: X fp32 -> bf16 (verified) --------------------------------------
__global__ __launch_bounds__(256) void cvt_x(const float* __restrict__ X, u16* __restrict__ Xb)
{
    const int idx0 = blockIdx.x * 256 + threadIdx.x;
    #pragma unroll
    for (int i = 0; i < 4; i++) {
        const int c = idx0 + i * 262144;
        const float4 v = *(const float4*)&X[(size_t)c * 4];
        ushort4 o;
        o.x = f2bf(v.x); o.y = f2bf(v.y); o.z = f2bf(v.z); o.w = f2bf(v.w);
        *(ushort4*)&Xb[(size_t)c * 4] = o;
    }
}

// ---------------- prep: W[k][n] fp32 -> W^T[n][k] bf16 (verified) ----------------------
__global__ __launch_bounds__(256) void trans_w(
    const float* __restrict__ W, u16* __restrict__ WT)
{
    __shared__ float L[32][33];
    const int k0 = blockIdx.x * 32, n0 = blockIdx.y * 32;
    const int tx = threadIdx.x & 31, ty = threadIdx.x >> 5;
    #pragma unroll
    for (int i = 0; i < 4; i++)
        L[ty + 8 * i][tx] = W[(size_t)(k0 + ty + 8 * i) * DD + n0 + tx];
    __syncthreads();
    #pragma unroll
    for (int i = 0; i < 4; i++) {
        const int n = ty + 8 * i;
        WT[(size_t)(n0 + n) * DD + k0 + tx] = f2bf(L[tx][n]);
    }
}

// ---------------- fused QKV GEMM, 128x256 tile on the verified BK=32 core --------------
// grid (12, 32): which = bx>>2; n0 = (bx&3)*256; m0 = by*128. 4 waves; wave tile 64x128.
__global__ __launch_bounds__(256) void gemm_qkv_n256(
    const u16* __restrict__ Xb, const u16* __restrict__ WTall, u16* __restrict__ QKVb)
{
    __shared__ __align__(16) u16 sm[24576];   // 48KB: 2 bufs x (A 8KB + B 16KB)
    const int tid = threadIdx.x;
    const int lane = tid & 63;
    const int w = tid >> 6;
    const int li = lane & 15, quad = lane >> 4;
    const int wr = w >> 1, wc = w & 1;
    const int which = blockIdx.x >> 2;
    const int n0 = (blockIdx.x & 3) * 256;
    const int m0 = blockIdx.y * 128;
    const u16* BT = WTall + (size_t)which * (DD * DD);
    u16* outp = QKVb + (size_t)which * ((size_t)BB * HH * SS * HDD);
    const float scale = (which == 0) ? 0.125f : 1.0f;

    const int srow = tid >> 2;          // 0..63
    const int scol = (tid & 3) * 8;     // 0,8,16,24

    uint4 ra[2], rb[4], na[2], nb[4];
    #pragma unroll
    for (int rr = 0; rr < 2; rr++)
        ra[rr] = *(const uint4*)(Xb + (size_t)(m0 + rr * 64 + srow) * DD + scol);
    #pragma unroll
    for (int rr = 0; rr < 4; rr++)
        rb[rr] = *(const uint4*)(BT + (size_t)(n0 + rr * 64 + srow) * DD + scol);

    f32x4 acc[4][8] = {};
    for (int t = 0; t < 32; t++) {
        u16* base = sm + (t & 1) * 12288;
        #pragma unroll
        for (int rr = 0; rr < 2; rr++)
            *(uint4*)&base[(rr * 64 + srow) * 32 + scol] = ra[rr];
        #pragma unroll
        for (int rr = 0; rr < 4; rr++)
            *(uint4*)&base[4096 + (rr * 64 + srow) * 32 + scol] = rb[rr];
        if (t < 31) {
            const int k1 = (t + 1) * 32;
            #pragma unroll
            for (int rr = 0; rr < 2; rr++)
                na[rr] = *(const uint4*)(Xb + (size_t)(m0 + rr * 64 + srow) * DD + k1 + scol);
            #pragma unroll
            for (int rr = 0; rr < 4; rr++)
                nb[rr] = *(const uint4*)(BT + (size_t)(n0 + rr * 64 + srow) * DD + k1 + scol);
        }
        __syncthreads();
        bf16x8 a[4], b[8];
        #pragma unroll
        for (int f = 0; f < 4; f++)
            a[f] = *(const bf16x8*)(base + (wr * 64 + f * 16 + li) * 32 + quad * 8);
        #pragma unroll
        for (int f8 = 0; f8 < 8; f8++)
            b[f8] = *(const bf16x8*)(base + 4096 + (wc * 128 + f8 * 16 + li) * 32 + quad * 8);
        #pragma unroll
        for (int fm = 0; fm < 4; fm++)
            #pragma unroll
            for (int f8 = 0; f8 < 8; f8++)
                acc[fm][f8] = __builtin_amdgcn_mfma_f32_16x16x32_bf16(
                    a[fm], b[f8], acc[fm][f8], 0, 0, 0);
        if (t < 31) {
            #pragma unroll
            for (int rr = 0; rr < 2; rr++) ra[rr] = na[rr];
            #pragma unroll
            for (int rr = 0; rr < 4; rr++) rb[rr] = nb[rr];
        }
        __syncthreads();
    }

    const int bidx = m0 >> 11;
    const int s0 = m0 & (SS - 1);
    if (which < 2) {
        // RoPE epilogue: verified two-pass pattern per n-half. Scatter wave: wr==p, wc==nh.
        float (*Ts)[128] = (float(*)[128])sm;
        #pragma unroll
        for (int nh = 0; nh < 2; nh++) {
            #pragma unroll
            for (int p = 0; p < 2; p++) {
                __syncthreads();
                if (wr == p && wc == nh) {
                    #pragma unroll
                    for (int fm = 0; fm < 4; fm++)
                        #pragma unroll
                        for (int f8 = 0; f8 < 8; f8++)
                            #pragma unroll
                            for (int r = 0; r < 4; r++)
                                Ts[fm * 16 + quad * 4 + r][f8 * 16 + li] = acc[fm][f8][r];
                }
                __syncthreads();
                const int n0h = n0 + nh * 128;
                #pragma unroll
                for (int i = 0; i < 4; i++) {
                    const int c = tid + 256 * i;     // 0..1023
                    const int mr = c >> 4;           // 0..63
                    const int nc = c & 15;           // 0..15
                    const int s = s0 + p * 64 + mr;
                    const int n = n0h + nc * 8;
                    const int h = n >> 6, hd0 = n & 63;
                    const float4 v0 = *(const float4*)&Ts[mr][nc * 8];
                    const float4 v1 = *(const float4*)&Ts[mr][nc * 8 + 4];
                    const float fs = (float)s;
                    u32 w0, w1, w2, w3;
                    {
                        const float inv = exp2f((float)((hd0 >> 1) + 0) * -0.4152410118609203f);
                        float sn, cs; sincosf(fs * inv, &sn, &cs);
                        w0 = (u32)f2bf((v0.x * cs - v0.y * sn) * scale) |
                             ((u32)f2bf((v0.x * sn + v0.y * cs) * scale) << 16);
                    }
                    {
                        const float inv = exp2f((float)((hd0 >> 1) + 1) * -0.4152410118609203f);
                        float sn, cs; sincosf(fs * inv, &sn, &cs);
                        w1 = (u32)f2bf((v0.z * cs - v0.w * sn) * scale) |
                             ((u32)f2bf((v0.z * sn + v0.w * cs) * scale) << 16);
                    }
                    {
                        const float inv = exp2f((float)((hd0 >> 1) + 2) * -0.4152410118609203f);
                        float sn, cs; sincosf(fs * inv, &sn, &cs);
                        w2 = (u32)f2bf((v1.x * cs - v1.y * sn) * scale) |
                             ((u32)f2bf((v1.x * sn + v1.y * cs) * scale) << 16);
                    }
                    {
                        const float inv = exp2f((float)((hd0 >> 1) + 3) * -0.4152410118609203f);
                        float sn, cs; sincosf(fs * inv, &sn, &cs);
                        w3 = (u32)f2bf((v1.z * cs - v1.w * sn) * scale) |
                             ((u32)f2bf((v1.z * sn + v1.w * cs) * scale) << 16);
                    }
                    uint4 ov; ov.x = w0; ov.y = w1; ov.z = w2; ov.w = w3;
                    *(uint4*)&outp[((size_t)(bidx * HH + h) * SS + s) * HDD + hd0] = ov;
                }
            }
        }
    } else {
        // V^T epilogue: verified two-pass pattern per n-half.
        float (*Ts)[64] = (float(*)[64])sm;
        #pragma unroll
        for (int nh = 0; nh < 2; nh++) {
            #pragma unroll
            for (int p = 0; p < 2; p++) {
                __syncthreads();
                if (wr == p && wc == nh) {
                    #pragma unroll
                    for (int fm = 0; fm < 4; fm++)
                        #pragma unroll
                        for (int f8 = 0; f8 < 8; f8++)
                            *(float4*)&Ts[f8 * 16 + li][fm * 16 + quad * 4] =
                                make_float4(acc[fm][f8][0], acc[fm][f8][1],
                                            acc[fm][f8][2], acc[fm][f8][3]);
                }
                __syncthreads();
                const int n0h = n0 + nh * 128;
                #pragma unroll
                for (int i = 0; i < 4; i++) {
                    const int c = tid + 256 * i;     // 0..1023
                    const int nr = c >> 3;           // 0..127
                    const int mc = c & 7;            // 0..7
                    const int n = n0h + nr;
                    const int h = n >> 6, hd = n & 63;
                    const float4 v0 = *(const float4*)&Ts[nr][mc * 8];
                    const float4 v1 = *(const float4*)&Ts[nr][mc * 8 + 4];
                    uint4 ov;
                    ov.x = (u32)f2bf(v0.x) | ((u32)f2bf(v0.y) << 16);
                    ov.y = (u32)f2bf(v0.z) | ((u32)f2bf(v0.w) << 16);
                    ov.z = (u32)f2bf(v1.x) | ((u32)f2bf(v1.y) << 16);
                    ov.w = (u32)f2bf(v1.z) | ((u32)f2bf(v1.w) << 16);
                    *(uint4*)&outp[((size_t)(bidx * HH + h) * HDD + hd) * SS + s0 + p * 64 + mc * 8] = ov;
                }
            }
        }
    }
}

// ---------------- MFMA flash attention: TWO q-tiles per block share K/V loads ----------
__global__ __launch_bounds__(256) void attn_mfma(
    const u16* __restrict__ Qb, const u16* __restrict__ Kb,
    const u16* __restrict__ Vt, u16* __restrict__ ctxb)
{
    __shared__ u16 Ks[64][72];      // [key][d]
    __shared__ u16 Vs[64][72];      // [d][key]  (from V^T)
    __shared__ u16 Ps[4][16][72];   // per-wave [q][key]
    const int tid = threadIdx.x;
    const int lane = tid & 63;
    const int w = tid >> 6;
    const int li = lane & 15;
    const int quad = lane >> 4;
    const int bh = blockIdx.y;
    const int q0 = (gridDim.x - 1 - (int)blockIdx.x) * 128;   // heavy blocks first

    bf16x8 aQA0, aQA1, aQB0, aQB1;
    {
        const u16* qa = Qb + ((size_t)bh * SS + q0 + 16 * w + li) * HDD + quad * 8;
        aQA0 = *(const bf16x8*)qa;
        aQA1 = *(const bf16x8*)(qa + 32);
        const u16* qb = qa + (size_t)64 * HDD;
        aQB0 = *(const bf16x8*)qb;
        aQB1 = *(const bf16x8*)(qb + 32);
    }

    f32x4 OA[4] = {}, OB[4] = {};
    float mA[4] = {-1e30f, -1e30f, -1e30f, -1e30f};
    float mB[4] = {-1e30f, -1e30f, -1e30f, -1e30f};
    float lA[4] = {}, lB[4] = {};

    const int ntA = (q0 >> 6) + 1;
    const int ntB = ntA + 1;
    const int krow = tid >> 3;
    const int kch = (tid & 7) * 8;

    // verified per-tile body (QK^T -> mask -> online softmax -> P -> PV)
    auto process = [&](const bf16x8& aQ0, const bf16x8& aQ1,
                       f32x4 (&O)[4], float (&m_r)[4], float (&l_r)[4], const bool diag) {
        f32x4 S[4];
        #pragma unroll
        for (int t = 0; t < 4; t++) {
            const bf16x8 b0 = *(const bf16x8*)&Ks[16 * t + li][quad * 8];
            const bf16x8 b1 = *(const bf16x8*)&Ks[16 * t + li][32 + quad * 8];
            f32x4 a2 = {};
            a2 = __builtin_amdgcn_mfma_f32_16x16x32_bf16(aQ0, b0, a2, 0, 0, 0);
            a2 = __builtin_amdgcn_mfma_f32_16x16x32_bf16(aQ1, b1, a2, 0, 0, 0);
            S[t] = a2;
        }
        if (diag) {
            #pragma unroll
            for (int t = 0; t < 4; t++)
                #pragma unroll
                for (int r = 0; r < 4; r++)
                    if (16 * t + li > 16 * w + quad * 4 + r) S[t][r] = -1e30f;
        }
        float p[4][4];
        #pragma unroll
        for (int r = 0; r < 4; r++) {
            float mt = fmaxf(fmaxf(S[0][r], S[1][r]), fmaxf(S[2][r], S[3][r]));
            #pragma unroll
            for (int off = 1; off < 16; off <<= 1)
                mt = fmaxf(mt, __shfl_xor(mt, off));
            const float mnew = fmaxf(m_r[r], mt);
            const float alpha = __expf(m_r[r] - mnew);
            float ls = 0.f;
            #pragma unroll
            for (int t = 0; t < 4; t++) {
                p[r][t] = __expf(S[t][r] - mnew);
                ls += p[r][t];
            }
            #pragma unroll
            for (int off = 1; off < 16; off <<= 1)
                ls += __shfl_xor(ls, off);
            l_r[r] = l_r[r] * alpha + ls;
            m_r[r] = mnew;
            #pragma unroll
            for (int t2 = 0; t2 < 4; t2++) O[t2][r] *= alpha;
        }
        #pragma unroll
        for (int r = 0; r < 4; r++)
            #pragma unroll
            for (int t = 0; t < 4; t++)
                Ps[w][quad * 4 + r][16 * t + li] = f2bf(p[r][t]);
        const bf16x8 aP0 = *(const bf16x8*)&Ps[w][li][quad * 8];
        const bf16x8 aP1 = *(const bf16x8*)&Ps[w][li][32 + quad * 8];
        #pragma unroll
        for (int t2 = 0; t2 < 4; t2++) {
            const bf16x8 b0 = *(const bf16x8*)&Vs[16 * t2 + li][quad * 8];
            const bf16x8 b1 = *(const bf16x8*)&Vs[16 * t2 + li][32 + quad * 8];
            O[t2] = __builtin_amdgcn_mfma_f32_16x16x32_bf16(aP0, b0, O[t2], 0, 0, 0);
            O[t2] = __builtin_amdgcn_mfma_f32_16x16x32_bf16(aP1, b1, O[t2], 0, 0, 0);
        }
    };

    for (int jt = 0; jt < ntB; jt++) {
        const int j0 = jt << 6;
        const uint4 k0v = *(const uint4*)(Kb + ((size_t)bh * SS + j0 + krow) * HDD + kch);
        const uint4 k1v = *(const uint4*)(Kb + ((size_t)bh * SS + j0 + 32 + krow) * HDD + kch);
        const uint4 v0v = *(const uint4*)(Vt + ((size_t)bh * HDD + krow) * SS + j0 + kch);
        const uint4 v1v = *(const uint4*)(Vt + ((size_t)bh * HDD + 32 + krow) * SS + j0 + kch);
        __syncthreads();
        *(uint4*)&Ks[krow][kch] = k0v;
        *(uint4*)&Ks[32 + krow][kch] = k1v;
        *(uint4*)&Vs[krow][kch] = v0v;
        *(uint4*)&Vs[32 + krow][kch] = v1v;
        __syncthreads();

        if (jt < ntA) process(aQA0, aQA1, OA, mA, lA, jt == ntA - 1);
        process(aQB0, aQB1, OB, mB, lB, jt == ntB - 1);
    }

    const int b = bh >> 4, h = bh & 15;
    #pragma unroll
    for (int r = 0; r < 4; r++) {
        const float invA = 1.f / lA[r];
        const float invB = 1.f / lB[r];
        const int rowA = q0 + 16 * w + quad * 4 + r;
        const int rowB = rowA + 64;
        #pragma unroll
        for (int t2 = 0; t2 < 4; t2++) {
            ctxb[((size_t)b * SS + rowA) * DD + h * HDD + 16 * t2 + li] = f2bf(OA[t2][r] * invA);
            ctxb[((size_t)b * SS + rowB) * DD + h * HDD + 16 * t2 + li] = f2bf(OB[t2][r] * invB);
        }
    }
}

// ---------------- output GEMM (R20-verified): ctx(bf16) @ WoT(bf16) -> fp32 ------------
__global__ __launch_bounds__(256) void gemm_out_mfma(
    const u16* __restrict__ Ab, const u16* __restrict__ WoT, float* __restrict__ out)
{
    __shared__ __align__(16) u16 sm[16384];   // 32KB
    const int tid = threadIdx.x;
    const int lane = tid & 63;
    const int w = tid >> 6;
    const int li = lane & 15, quad = lane >> 4;
    const int wr = w >> 1, wc = w & 1;
    const int n0 = blockIdx.x * 128;
    const int m0 = blockIdx.y * 128;

    const int srow = tid >> 2;          // 0..63
    const int scol = (tid & 3) * 8;     // 0,8,16,24

    uint4 ra[2], rb[2], na[2], nb[2];
    #pragma unroll
    for (int rr = 0; rr < 2; rr++) {
        ra[rr] = *(const uint4*)(Ab  + (size_t)(m0 + rr * 64 + srow) * DD + scol);
        rb[rr] = *(const uint4*)(WoT + (size_t)(n0 + rr * 64 + srow) * DD + scol);
    }

    f32x4 acc[4][4] = {};
    for (int t = 0; t < 32; t++) {
        u16* base = sm + (t & 1) * 8192;
        #pragma unroll
        for (int rr = 0; rr < 2; rr++) {
            *(uint4*)&base[(rr * 64 + srow) * 32 + scol] = ra[rr];
            *(uint4*)&base[4096 + (rr * 64 + srow) * 32 + scol] = rb[rr];
        }
        if (t < 31) {
            const int k1 = (t + 1) * 32;
            #pragma unroll
            for (int rr = 0; rr < 2; rr++) {
                na[rr] = *(const uint4*)(Ab  + (size_t)(m0 + rr * 64 + srow) * DD + k1 + scol);
                nb[rr] = *(const uint4*)(WoT + (size_t)(n0 + rr * 64 + srow) * DD + k1 + scol);
            }
        }
        __syncthreads();
        bf16x8 a[4], b[4];
        #pragma unroll
        for (int f = 0; f < 4; f++) {
            a[f] = *(const bf16x8*)(base + (wr * 64 + f * 16 + li) * 32 + quad * 8);
            b[f] = *(const bf16x8*)(base + 4096 + (wc * 64 + f * 16 + li) * 32 + quad * 8);
        }
        #pragma unroll
        for (int fm = 0; fm < 4; fm++)
            #pragma unroll
            for (int fn = 0; fn < 4; fn++)
                acc[fm][fn] = __builtin_amdgcn_mfma_f32_16x16x32_bf16(
                    a[fm], b[fn], acc[fm][fn], 0, 0, 0);
        if (t < 31) {
            #pragma unroll
            for (int rr = 0; rr < 2; rr++) { ra[rr] = na[rr]; rb[rr] = nb[rr]; }
        }
        __syncthreads();
    }

    #pragma unroll
    for (int fm = 0; fm < 4; fm++)
        #pragma unroll
        for (int r = 0; r < 4; r++) {
            const size_t mg = (size_t)(m0 + wr * 64 + fm * 16 + quad * 4 + r) * DD;
            #pragma unroll
            for (int fn = 0; fn < 4; fn++)
                out[mg + n0 + wc * 64 + fn * 16 + li] = acc[fm][fn][r];
        }
}

extern "C" void kernel_launch(void* const* d_in, const int* in_sizes, int n_in,
                              void* d_out, int out_size, void* d_ws, size_t ws_size,
                              hipStream_t stream) {
    const float* x  = (const float*)d_in[0];
    const float* Wq = (const float*)d_in[1];
    const float* Wk = (const float*)d_in[2];
    const float* Wv = (const float*)d_in[3];
    const float* Wo = (const float*)d_in[4];
    float* out = (float*)d_out;

    u16* ws16 = (u16*)d_ws;
    const size_t E = 4194304;                 // B*H*S*HD elems
    const size_t M = 1048576;                 // D*D elems
    u16* QKVb = ws16;                         // [0,3E): Qb|Kb|Vt contiguous
    u16* Qb   = QKVb;
    u16* Kb   = QKVb + E;
    u16* Vt   = QKVb + 2 * E;
    u16* Xb   = ws16 + 3 * E;                 // [3E,4E), dead after QKV GEMM
    u16* ctxb = Xb;                           // reuse after QKV
    u16* WTall = ws16 + 4 * E;                // [4E,4E+3M): WqT|WkT|WvT contiguous
    u16* WoT  = WTall + 3 * M;                // [4E+3M, 4E+4M)  => 40 MiB total

    hipLaunchKernelGGL(cvt_x, dim3(1024), dim3(256), 0, stream, x, Xb);
    hipLaunchKernelGGL(trans_w, dim3(32, 32), dim3(256), 0, stream, Wq, WTall);
    hipLaunchKernelGGL(trans_w, dim3(32, 32), dim3(256), 0, stream, Wk, WTall + M);
    hipLaunchKernelGGL(trans_w, dim3(32, 32), dim3(256), 0, stream, Wv, WTall + 2 * M);
    hipLaunchKernelGGL(trans_w, dim3(32, 32), dim3(256), 0, stream, Wo, WoT);
    hipLaunchKernelGGL(gemm_qkv_n256, dim3(12, 32), dim3(256), 0, stream, Xb, WTall, QKVb);
    hipLaunchKernelGGL(attn_mfma, dim3(SS / 128, BB * HH), dim3(256), 0, stream,
                       Qb, Kb, Vt, ctxb);
    hipLaunchKernelGGL(gemm_out_mfma, dim3(8, 32), dim3(256), 0, stream, ctxb, WoT, out);
}

// Round 9
// 275.984 us; speedup vs baseline: 1.8238x; 1.8238x over previous
//
#include <hip/hip_runtime.h>
#include <cstdint>
#include <cstddef>

// B=2, S=2048, D=1024, H=16, HD=64. Inputs fp32, output fp32.
// R22: occupancy attack. QKV + out GEMMs retiled to 64x128 (wave-tile 32x64,
// acc[2][4]=32 VGPR) -> grid 1536 / 512 blocks (5-6 / 2 blocks/CU vs 3 / 1).
// Staging via global_load_lds width16 (PROVEN correct: R15==R16 bit-identical),
// linear LDS, BK=32, 1 barrier/K-step. Single-pass epilogues (Ts fits 32KB once):
// RoPE/V^T store loops are R19/R18 verbatim minus the p-loop. attn = R21 verbatim
// (two q-tiles sharing K/V). Preps unchanged.
// ws (40MiB): QKV[0,24M) contiguous; Xb[24,32M)->ctxb; WTall[32,38M); WoT[38,40M).
#define BB 2
#define SS 2048
#define DD 1024
#define HH 16
#define HDD 64

typedef unsigned short u16;
typedef unsigned int u32;
typedef __attribute__((ext_vector_type(8))) short bf16x8;
typedef __attribute__((ext_vector_type(4))) float f32x4;

__device__ __forceinline__ u16 f2bf(float f) {
    union { float f; u32 u; } c; c.f = f;
    u32 r = c.u + 0x7fffu + ((c.u >> 16) & 1u);  // RNE
    return (u16)(r >> 16);
}
__device__ __forceinline__ void gll16(const void* g, void* l) {
    __builtin_amdgcn_global_load_lds(
        (const __attribute__((address_space(1))) void*)g,
        (__attribute__((address_space(3))) void*)l, 16, 0, 0);
}

// ---------------- prep: X fp32 -> bf16 (verified) --------------------------------------
__global__ __launch_bounds__(256) void cvt_x(const float* __restrict__ X, u16* __restrict__ Xb)
{
    const int idx0 = blockIdx.x * 256 + threadIdx.x;
    #pragma unroll
    for (int i = 0; i < 4; i++) {
        const int c = idx0 + i * 262144;
        const float4 v = *(const float4*)&X[(size_t)c * 4];
        ushort4 o;
        o.x = f2bf(v.x); o.y = f2bf(v.y); o.z = f2bf(v.z); o.w = f2bf(v.w);
        *(ushort4*)&Xb[(size_t)c * 4] = o;
    }
}

// ---------------- prep: W[k][n] fp32 -> W^T[n][k] bf16 (verified) ----------------------
__global__ __launch_bounds__(256) void trans_w(
    const float* __restrict__ W, u16* __restrict__ WT)
{
    __shared__ float L[32][33];
    const int k0 = blockIdx.x * 32, n0 = blockIdx.y * 32;
    const int tx = threadIdx.x & 31, ty = threadIdx.x >> 5;
    #pragma unroll
    for (int i = 0; i < 4; i++)
        L[ty + 8 * i][tx] = W[(size_t)(k0 + ty + 8 * i) * DD + n0 + tx];
    __syncthreads();
    #pragma unroll
    for (int i = 0; i < 4; i++) {
        const int n = ty + 8 * i;
        WT[(size_t)(n0 + n) * DD + k0 + tx] = f2bf(L[tx][n]);
    }
}

// ---------------- fused QKV GEMM: 64x128 tile, BK=32, gll16 staging --------------------
// grid (24, 64): which = bx>>3; n0 = (bx&7)*128; m0 = by*64. 4 waves, wave-tile 32x64.
// LDS: dbuf 2 x (A 4KB + B 8KB) = 24KB staging; epilogue Ts fp32 32KB (single pass).
__global__ __launch_bounds__(256) void gemm_qkv(
    const u16* __restrict__ Xb, const u16* __restrict__ WTall, u16* __restrict__ QKVb)
{
    __shared__ __align__(16) u16 sm[16384];   // 32KB (staging uses first 24KB)
    const int tid = threadIdx.x;
    const int lane = tid & 63;
    const int w = tid >> 6;
    const int li = lane & 15, quad = lane >> 4;
    const int wr = w >> 1, wc = w & 1;
    const int which = blockIdx.x >> 3;
    const int n0 = (blockIdx.x & 7) * 128;
    const int m0 = blockIdx.y * 64;
    const u16* BT = WTall + (size_t)which * (DD * DD);
    u16* outp = QKVb + (size_t)which * ((size_t)BB * HH * SS * HDD);
    const float scale = (which == 0) ? 0.125f : 1.0f;

    // A source byte = tid*16 within 64x32-u16 tile; B = rr*4096 + tid*16 within 128x32.
    const int arow = tid >> 2;            // 0..63
    const int acol = (tid & 3) * 8;       // 0,8,16,24
    const int wbase = (tid >> 6) * 1024;  // wave-uniform LDS byte base

    auto stage = [&](int t, int buf) {
        char* base = (char*)(sm + buf * 6144);
        const int k0 = t * 32;
        gll16(Xb + (size_t)(m0 + arow) * DD + k0 + acol, base + wbase);
        #pragma unroll
        for (int rr = 0; rr < 2; rr++)
            gll16(BT + (size_t)(n0 + rr * 64 + arow) * DD + k0 + acol,
                  base + 4096 + rr * 4096 + wbase);
    };

    f32x4 acc[2][4] = {};
    stage(0, 0);
    __syncthreads();
    for (int t = 0; t < 32; t++) {
        const int buf = t & 1;
        if (t < 31) stage(t + 1, buf ^ 1);
        const u16* tA = sm + buf * 6144;
        const u16* tB = tA + 2048;
        bf16x8 a[2], b[4];
        #pragma unroll
        for (int f = 0; f < 2; f++)
            a[f] = *(const bf16x8*)(tA + (wr * 32 + f * 16 + li) * 32 + quad * 8);
        #pragma unroll
        for (int f = 0; f < 4; f++)
            b[f] = *(const bf16x8*)(tB + (wc * 64 + f * 16 + li) * 32 + quad * 8);
        #pragma unroll
        for (int fm = 0; fm < 2; fm++)
            #pragma unroll
            for (int fn = 0; fn < 4; fn++)
                acc[fm][fn] = __builtin_amdgcn_mfma_f32_16x16x32_bf16(
                    a[fm], b[fn], acc[fm][fn], 0, 0, 0);
        __syncthreads();   // drains gll16 for buf^1 AND protects buf for next overwrite
    }

    const int bidx = m0 >> 11;
    const int s0 = m0 & (SS - 1);
    if (which < 2) {
        // RoPE epilogue (R19-verified store loop, single pass): Ts[m 64][n 128] fp32.
        float (*Ts)[128] = (float(*)[128])sm;
        #pragma unroll
        for (int fm = 0; fm < 2; fm++)
            #pragma unroll
            for (int fn = 0; fn < 4; fn++)
                #pragma unroll
                for (int r = 0; r < 4; r++)
                    Ts[wr * 32 + fm * 16 + quad * 4 + r][wc * 64 + fn * 16 + li] = acc[fm][fn][r];
        __syncthreads();
        #pragma unroll
        for (int i = 0; i < 4; i++) {
            const int c = tid + 256 * i;     // 0..1023
            const int mr = c >> 4;           // 0..63
            const int nc = c & 15;           // 0..15
            const int s = s0 + mr;
            const int n = n0 + nc * 8;
            const int h = n >> 6, hd0 = n & 63;
            const float4 v0 = *(const float4*)&Ts[mr][nc * 8];
            const float4 v1 = *(const float4*)&Ts[mr][nc * 8 + 4];
            const float fs = (float)s;
            u32 w0, w1, w2, w3;
            {
                const float inv = exp2f((float)((hd0 >> 1) + 0) * -0.4152410118609203f);
                float sn, cs; sincosf(fs * inv, &sn, &cs);
                w0 = (u32)f2bf((v0.x * cs - v0.y * sn) * scale) |
                     ((u32)f2bf((v0.x * sn + v0.y * cs) * scale) << 16);
            }
            {
                const float inv = exp2f((float)((hd0 >> 1) + 1) * -0.4152410118609203f);
                float sn, cs; sincosf(fs * inv, &sn, &cs);
                w1 = (u32)f2bf((v0.z * cs - v0.w * sn) * scale) |
                     ((u32)f2bf((v0.z * sn + v0.w * cs) * scale) << 16);
            }
            {
                const float inv = exp2f((float)((hd0 >> 1) + 2) * -0.4152410118609203f);
                float sn, cs; sincosf(fs * inv, &sn, &cs);
                w2 = (u32)f2bf((v1.x * cs - v1.y * sn) * scale) |
                     ((u32)f2bf((v1.x * sn + v1.y * cs) * scale) << 16);
            }
            {
                const float inv = exp2f((float)((hd0 >> 1) + 3) * -0.4152410118609203f);
                float sn, cs; sincosf(fs * inv, &sn, &cs);
                w3 = (u32)f2bf((v1.z * cs - v1.w * sn) * scale) |
                     ((u32)f2bf((v1.z * sn + v1.w * cs) * scale) << 16);
            }
            uint4 ov; ov.x = w0; ov.y = w1; ov.z = w2; ov.w = w3;
            *(uint4*)&outp[((size_t)(bidx * HH + h) * SS + s) * HDD + hd0] = ov;
        }
    } else {
        // V^T epilogue (R18-verified store loop, single pass): Ts[n 128][m 64] fp32.
        float (*Ts)[64] = (float(*)[64])sm;
        #pragma unroll
        for (int fm = 0; fm < 2; fm++)
            #pragma unroll
            for (int fn = 0; fn < 4; fn++)
                *(float4*)&Ts[wc * 64 + fn * 16 + li][wr * 32 + fm * 16 + quad * 4] =
                    make_float4(acc[fm][fn][0], acc[fm][fn][1],
                                acc[fm][fn][2], acc[fm][fn][3]);
        __syncthreads();
        #pragma unroll
        for (int i = 0; i < 4; i++) {
            const int c = tid + 256 * i;     // 0..1023
            const int nr = c >> 3;           // 0..127
            const int mc = c & 7;            // 0..7
            const int n = n0 + nr;
            const int h = n >> 6, hd = n & 63;
            const float4 v0 = *(const float4*)&Ts[nr][mc * 8];
            const float4 v1 = *(const float4*)&Ts[nr][mc * 8 + 4];
            uint4 ov;
            ov.x = (u32)f2bf(v0.x) | ((u32)f2bf(v0.y) << 16);
            ov.y = (u32)f2bf(v0.z) | ((u32)f2bf(v0.w) << 16);
            ov.z = (u32)f2bf(v1.x) | ((u32)f2bf(v1.y) << 16);
            ov.w = (u32)f2bf(v1.z) | ((u32)f2bf(v1.w) << 16);
            *(uint4*)&outp[((size_t)(bidx * HH + h) * HDD + hd) * SS + s0 + mc * 8] = ov;
        }
    }
}

// ---------------- MFMA flash attention (R21 verbatim): two q-tiles share K/V -----------
__global__ __launch_bounds__(256) void attn_mfma(
    const u16* __restrict__ Qb, const u16* __restrict__ Kb,
    const u16* __restrict__ Vt, u16* __restrict__ ctxb)
{
    __shared__ u16 Ks[64][72];      // [key][d]
    __shared__ u16 Vs[64][72];      // [d][key]  (from V^T)
    __shared__ u16 Ps[4][16][72];   // per-wave [q][key]
    const int tid = threadIdx.x;
    const int lane = tid & 63;
    const int w = tid >> 6;
    const int li = lane & 15;
    const int quad = lane >> 4;
    const int bh = blockIdx.y;
    const int q0 = (gridDim.x - 1 - (int)blockIdx.x) * 128;   // heavy blocks first

    bf16x8 aQA0, aQA1, aQB0, aQB1;
    {
        const u16* qa = Qb + ((size_t)bh * SS + q0 + 16 * w + li) * HDD + quad * 8;
        aQA0 = *(const bf16x8*)qa;
        aQA1 = *(const bf16x8*)(qa + 32);
        const u16* qb = qa + (size_t)64 * HDD;
        aQB0 = *(const bf16x8*)qb;
        aQB1 = *(const bf16x8*)(qb + 32);
    }

    f32x4 OA[4] = {}, OB[4] = {};
    float mA[4] = {-1e30f, -1e30f, -1e30f, -1e30f};
    float mB[4] = {-1e30f, -1e30f, -1e30f, -1e30f};
    float lA[4] = {}, lB[4] = {};

    const int ntA = (q0 >> 6) + 1;
    const int ntB = ntA + 1;
    const int krow = tid >> 3;
    const int kch = (tid & 7) * 8;

    auto process = [&](const bf16x8& aQ0, const bf16x8& aQ1,
                       f32x4 (&O)[4], float (&m_r)[4], float (&l_r)[4], const bool diag) {
        f32x4 S[4];
        #pragma unroll
        for (int t = 0; t < 4; t++) {
            const bf16x8 b0 = *(const bf16x8*)&Ks[16 * t + li][quad * 8];
            const bf16x8 b1 = *(const bf16x8*)&Ks[16 * t + li][32 + quad * 8];
            f32x4 a2 = {};
            a2 = __builtin_amdgcn_mfma_f32_16x16x32_bf16(aQ0, b0, a2, 0, 0, 0);
            a2 = __builtin_amdgcn_mfma_f32_16x16x32_bf16(aQ1, b1, a2, 0, 0, 0);
            S[t] = a2;
        }
        if (diag) {
            #pragma unroll
            for (int t = 0; t < 4; t++)
                #pragma unroll
                for (int r = 0; r < 4; r++)
                    if (16 * t + li > 16 * w + quad * 4 + r) S[t][r] = -1e30f;
        }
        float p[4][4];
        #pragma unroll
        for (int r = 0; r < 4; r++) {
            float mt = fmaxf(fmaxf(S[0][r], S[1][r]), fmaxf(S[2][r], S[3][r]));
            #pragma unroll
            for (int off = 1; off < 16; off <<= 1)
                mt = fmaxf(mt, __shfl_xor(mt, off));
            const float mnew = fmaxf(m_r[r], mt);
            const float alpha = __expf(m_r[r] - mnew);
            float ls = 0.f;
            #pragma unroll
            for (int t = 0; t < 4; t++) {
                p[r][t] = __expf(S[t][r] - mnew);
                ls += p[r][t];
            }
            #pragma unroll
            for (int off = 1; off < 16; off <<= 1)
                ls += __shfl_xor(ls, off);
            l_r[r] = l_r[r] * alpha + ls;
            m_r[r] = mnew;
            #pragma unroll
            for (int t2 = 0; t2 < 4; t2++) O[t2][r] *= alpha;
        }
        #pragma unroll
        for (int r = 0; r < 4; r++)
            #pragma unroll
            for (int t = 0; t < 4; t++)
                Ps[w][quad * 4 + r][16 * t + li] = f2bf(p[r][t]);
        const bf16x8 aP0 = *(const bf16x8*)&Ps[w][li][quad * 8];
        const bf16x8 aP1 = *(const bf16x8*)&Ps[w][li][32 + quad * 8];
        #pragma unroll
        for (int t2 = 0; t2 < 4; t2++) {
            const bf16x8 b0 = *(const bf16x8*)&Vs[16 * t2 + li][quad * 8];
            const bf16x8 b1 = *(const bf16x8*)&Vs[16 * t2 + li][32 + quad * 8];
            O[t2] = __builtin_amdgcn_mfma_f32_16x16x32_bf16(aP0, b0, O[t2], 0, 0, 0);
            O[t2] = __builtin_amdgcn_mfma_f32_16x16x32_bf16(aP1, b1, O[t2], 0, 0, 0);
        }
    };

    for (int jt = 0; jt < ntB; jt++) {
        const int j0 = jt << 6;
        const uint4 k0v = *(const uint4*)(Kb + ((size_t)bh * SS + j0 + krow) * HDD + kch);
        const uint4 k1v = *(const uint4*)(Kb + ((size_t)bh * SS + j0 + 32 + krow) * HDD + kch);
        const uint4 v0v = *(const uint4*)(Vt + ((size_t)bh * HDD + krow) * SS + j0 + kch);
        const uint4 v1v = *(const uint4*)(Vt + ((size_t)bh * HDD + 32 + krow) * SS + j0 + kch);
        __syncthreads();
        *(uint4*)&Ks[krow][kch] = k0v;
        *(uint4*)&Ks[32 + krow][kch] = k1v;
        *(uint4*)&Vs[krow][kch] = v0v;
        *(uint4*)&Vs[32 + krow][kch] = v1v;
        __syncthreads();

        if (jt < ntA) process(aQA0, aQA1, OA, mA, lA, jt == ntA - 1);
        process(aQB0, aQB1, OB, mB, lB, jt == ntB - 1);
    }

    const int b = bh >> 4, h = bh & 15;
    #pragma unroll
    for (int r = 0; r < 4; r++) {
        const float invA = 1.f / lA[r];
        const float invB = 1.f / lB[r];
        const int rowA = q0 + 16 * w + quad * 4 + r;
        const int rowB = rowA + 64;
        #pragma unroll
        for (int t2 = 0; t2 < 4; t2++) {
            ctxb[((size_t)b * SS + rowA) * DD + h * HDD + 16 * t2 + li] = f2bf(OA[t2][r] * invA);
            ctxb[((size_t)b * SS + rowB) * DD + h * HDD + 16 * t2 + li] = f2bf(OB[t2][r] * invB);
        }
    }
}

// ---------------- output GEMM: 64x128 tile, gll16 staging, direct fp32 stores ----------
// grid (8, 64). Verified C-layout: row = quad*4+r, col = li.
__global__ __launch_bounds__(256) void gemm_out_mfma(
    const u16* __restrict__ Ab, const u16* __restrict__ WoT, float* __restrict__ out)
{
    __shared__ __align__(16) u16 sm[12288];   // 24KB: 2 bufs x (A 4KB + B 8KB)
    const int tid = threadIdx.x;
    const int lane = tid & 63;
    const int w = tid >> 6;
    const int li = lane & 15, quad = lane >> 4;
    const int wr = w >> 1, wc = w & 1;
    const int n0 = blockIdx.x * 128;
    const int m0 = blockIdx.y * 64;

    const int arow = tid >> 2;
    const int acol = (tid & 3) * 8;
    const int wbase = (tid >> 6) * 1024;

    auto stage = [&](int t, int buf) {
        char* base = (char*)(sm + buf * 6144);
        const int k0 = t * 32;
        gll16(Ab + (size_t)(m0 + arow) * DD + k0 + acol, base + wbase);
        #pragma unroll
        for (int rr = 0; rr < 2; rr++)
            gll16(WoT + (size_t)(n0 + rr * 64 + arow) * DD + k0 + acol,
                  base + 4096 + rr * 4096 + wbase);
    };

    f32x4 acc[2][4] = {};
    stage(0, 0);
    __syncthreads();
    for (int t = 0; t < 32; t++) {
        const int buf = t & 1;
        if (t < 31) stage(t + 1, buf ^ 1);
        const u16* tA = sm + buf * 6144;
        const u16* tB = tA + 2048;
        bf16x8 a[2], b[4];
        #pragma unroll
        for (int f = 0; f < 2; f++)
            a[f] = *(const bf16x8*)(tA + (wr * 32 + f * 16 + li) * 32 + quad * 8);
        #pragma unroll
        for (int f = 0; f < 4; f++)
            b[f] = *(const bf16x8*)(tB + (wc * 64 + f * 16 + li) * 32 + quad * 8);
        #pragma unroll
        for (int fm = 0; fm < 2; fm++)
            #pragma unroll
            for (int fn = 0; fn < 4; fn++)
                acc[fm][fn] = __builtin_amdgcn_mfma_f32_16x16x32_bf16(
                    a[fm], b[fn], acc[fm][fn], 0, 0, 0);
        __syncthreads();
    }

    #pragma unroll
    for (int fm = 0; fm < 2; fm++)
        #pragma unroll
        for (int r = 0; r < 4; r++) {
            const size_t mg = (size_t)(m0 + wr * 32 + fm * 16 + quad * 4 + r) * DD;
            #pragma unroll
            for (int fn = 0; fn < 4; fn++)
                out[mg + n0 + wc * 64 + fn * 16 + li] = acc[fm][fn][r];
        }
}

extern "C" void kernel_launch(void* const* d_in, const int* in_sizes, int n_in,
                              void* d_out, int out_size, void* d_ws, size_t ws_size,
                              hipStream_t stream) {
    const float* x  = (const float*)d_in[0];
    const float* Wq = (const float*)d_in[1];
    const float* Wk = (const float*)d_in[2];
    const float* Wv = (const float*)d_in[3];
    const float* Wo = (const float*)d_in[4];
    float* out = (float*)d_out;

    u16* ws16 = (u16*)d_ws;
    const size_t E = 4194304;                 // B*H*S*HD elems
    const size_t M = 1048576;                 // D*D elems
    u16* QKVb = ws16;                         // [0,3E): Qb|Kb|Vt contiguous
    u16* Qb   = QKVb;
    u16* Kb   = QKVb + E;
    u16* Vt   = QKVb + 2 * E;
    u16* Xb   = ws16 + 3 * E;                 // [3E,4E), dead after QKV GEMM
    u16* ctxb = Xb;                           // reuse after QKV
    u16* WTall = ws16 + 4 * E;                // [4E,4E+3M): WqT|WkT|WvT contiguous
    u16* WoT  = WTall + 3 * M;                // [4E+3M, 4E+4M)  => 40 MiB total

    hipLaunchKernelGGL(cvt_x, dim3(1024), dim3(256), 0, stream, x, Xb);
    hipLaunchKernelGGL(trans_w, dim3(32, 32), dim3(256), 0, stream, Wq, WTall);
    hipLaunchKernelGGL(trans_w, dim3(32, 32), dim3(256), 0, stream, Wk, WTall + M);
    hipLaunchKernelGGL(trans_w, dim3(32, 32), dim3(256), 0, stream, Wv, WTall + 2 * M);
    hipLaunchKernelGGL(trans_w, dim3(32, 32), dim3(256), 0, stream, Wo, WoT);
    hipLaunchKernelGGL(gemm_qkv, dim3(24, 64), dim3(256), 0, stream, Xb, WTall, QKVb);
    hipLaunchKernelGGL(attn_mfma, dim3(SS / 128, BB * HH), dim3(256), 0, stream,
                       Qb, Kb, Vt, ctxb);
    hipLaunchKernelGGL(gemm_out_mfma, dim3(8, 64), dim3(256), 0, stream, ctxb, WoT, out);
}

// Round 10
// 261.285 us; speedup vs baseline: 1.9264x; 1.0563x over previous
//
#include <hip/hip_runtime.h>
#include <cstdint>
#include <cstddef>

// B=2, S=2048, D=1024, H=16, HD=64. Inputs fp32, output fp32.
// R23: attn widened to 8 waves / 512 threads per block (same 128 q-rows per block:
// each wave owns one 16-row strip; waves 0-3 run ntA tiles, 4-7 run ntA+1 with the
// R21-verified skip pattern; diag mask row base = 16*(w&3)). K/V staging shared by
// 8 waves (1 uint4 K + 1 uint4 V per thread). Occupancy 8 -> 16-32 waves/CU.
// QKV/out GEMMs + preps = R22 verbatim (verified).
// ws (40MiB): QKV[0,24M) contiguous; Xb[24,32M)->ctxb; WTall[32,38M); WoT[38,40M).
#define BB 2
#define SS 2048
#define DD 1024
#define HH 16
#define HDD 64

typedef unsigned short u16;
typedef unsigned int u32;
typedef __attribute__((ext_vector_type(8))) short bf16x8;
typedef __attribute__((ext_vector_type(4))) float f32x4;

__device__ __forceinline__ u16 f2bf(float f) {
    union { float f; u32 u; } c; c.f = f;
    u32 r = c.u + 0x7fffu + ((c.u >> 16) & 1u);  // RNE
    return (u16)(r >> 16);
}
__device__ __forceinline__ void gll16(const void* g, void* l) {
    __builtin_amdgcn_global_load_lds(
        (const __attribute__((address_space(1))) void*)g,
        (__attribute__((address_space(3))) void*)l, 16, 0, 0);
}

// ---------------- prep: X fp32 -> bf16 (verified) --------------------------------------
__global__ __launch_bounds__(256) void cvt_x(const float* __restrict__ X, u16* __restrict__ Xb)
{
    const int idx0 = blockIdx.x * 256 + threadIdx.x;
    #pragma unroll
    for (int i = 0; i < 4; i++) {
        const int c = idx0 + i * 262144;
        const float4 v = *(const float4*)&X[(size_t)c * 4];
        ushort4 o;
        o.x = f2bf(v.x); o.y = f2bf(v.y); o.z = f2bf(v.z); o.w = f2bf(v.w);
        *(ushort4*)&Xb[(size_t)c * 4] = o;
    }
}

// ---------------- prep: W[k][n] fp32 -> W^T[n][k] bf16 (verified) ----------------------
__global__ __launch_bounds__(256) void trans_w(
    const float* __restrict__ W, u16* __restrict__ WT)
{
    __shared__ float L[32][33];
    const int k0 = blockIdx.x * 32, n0 = blockIdx.y * 32;
    const int tx = threadIdx.x & 31, ty = threadIdx.x >> 5;
    #pragma unroll
    for (int i = 0; i < 4; i++)
        L[ty + 8 * i][tx] = W[(size_t)(k0 + ty + 8 * i) * DD + n0 + tx];
    __syncthreads();
    #pragma unroll
    for (int i = 0; i < 4; i++) {
        const int n = ty + 8 * i;
        WT[(size_t)(n0 + n) * DD + k0 + tx] = f2bf(L[tx][n]);
    }
}

// ---------------- fused QKV GEMM (R22 verbatim): 64x128 tile, BK=32, gll16 -------------
__global__ __launch_bounds__(256) void gemm_qkv(
    const u16* __restrict__ Xb, const u16* __restrict__ WTall, u16* __restrict__ QKVb)
{
    __shared__ __align__(16) u16 sm[16384];   // 32KB (staging uses first 24KB)
    const int tid = threadIdx.x;
    const int lane = tid & 63;
    const int w = tid >> 6;
    const int li = lane & 15, quad = lane >> 4;
    const int wr = w >> 1, wc = w & 1;
    const int which = blockIdx.x >> 3;
    const int n0 = (blockIdx.x & 7) * 128;
    const int m0 = blockIdx.y * 64;
    const u16* BT = WTall + (size_t)which * (DD * DD);
    u16* outp = QKVb + (size_t)which * ((size_t)BB * HH * SS * HDD);
    const float scale = (which == 0) ? 0.125f : 1.0f;

    const int arow = tid >> 2;            // 0..63
    const int acol = (tid & 3) * 8;       // 0,8,16,24
    const int wbase = (tid >> 6) * 1024;  // wave-uniform LDS byte base

    auto stage = [&](int t, int buf) {
        char* base = (char*)(sm + buf * 6144);
        const int k0 = t * 32;
        gll16(Xb + (size_t)(m0 + arow) * DD + k0 + acol, base + wbase);
        #pragma unroll
        for (int rr = 0; rr < 2; rr++)
            gll16(BT + (size_t)(n0 + rr * 64 + arow) * DD + k0 + acol,
                  base + 4096 + rr * 4096 + wbase);
    };

    f32x4 acc[2][4] = {};
    stage(0, 0);
    __syncthreads();
    for (int t = 0; t < 32; t++) {
        const int buf = t & 1;
        if (t < 31) stage(t + 1, buf ^ 1);
        const u16* tA = sm + buf * 6144;
        const u16* tB = tA + 2048;
        bf16x8 a[2], b[4];
        #pragma unroll
        for (int f = 0; f < 2; f++)
            a[f] = *(const bf16x8*)(tA + (wr * 32 + f * 16 + li) * 32 + quad * 8);
        #pragma unroll
        for (int f = 0; f < 4; f++)
            b[f] = *(const bf16x8*)(tB + (wc * 64 + f * 16 + li) * 32 + quad * 8);
        #pragma unroll
        for (int fm = 0; fm < 2; fm++)
            #pragma unroll
            for (int fn = 0; fn < 4; fn++)
                acc[fm][fn] = __builtin_amdgcn_mfma_f32_16x16x32_bf16(
                    a[fm], b[fn], acc[fm][fn], 0, 0, 0);
        __syncthreads();
    }

    const int bidx = m0 >> 11;
    const int s0 = m0 & (SS - 1);
    if (which < 2) {
        float (*Ts)[128] = (float(*)[128])sm;
        #pragma unroll
        for (int fm = 0; fm < 2; fm++)
            #pragma unroll
            for (int fn = 0; fn < 4; fn++)
                #pragma unroll
                for (int r = 0; r < 4; r++)
                    Ts[wr * 32 + fm * 16 + quad * 4 + r][wc * 64 + fn * 16 + li] = acc[fm][fn][r];
        __syncthreads();
        #pragma unroll
        for (int i = 0; i < 4; i++) {
            const int c = tid + 256 * i;     // 0..1023
            const int mr = c >> 4;           // 0..63
            const int nc = c & 15;           // 0..15
            const int s = s0 + mr;
            const int n = n0 + nc * 8;
            const int h = n >> 6, hd0 = n & 63;
            const float4 v0 = *(const float4*)&Ts[mr][nc * 8];
            const float4 v1 = *(const float4*)&Ts[mr][nc * 8 + 4];
            const float fs = (float)s;
            u32 w0, w1, w2, w3;
            {
                const float inv = exp2f((float)((hd0 >> 1) + 0) * -0.4152410118609203f);
                float sn, cs; sincosf(fs * inv, &sn, &cs);
                w0 = (u32)f2bf((v0.x * cs - v0.y * sn) * scale) |
                     ((u32)f2bf((v0.x * sn + v0.y * cs) * scale) << 16);
            }
            {
                const float inv = exp2f((float)((hd0 >> 1) + 1) * -0.4152410118609203f);
                float sn, cs; sincosf(fs * inv, &sn, &cs);
                w1 = (u32)f2bf((v0.z * cs - v0.w * sn) * scale) |
                     ((u32)f2bf((v0.z * sn + v0.w * cs) * scale) << 16);
            }
            {
                const float inv = exp2f((float)((hd0 >> 1) + 2) * -0.4152410118609203f);
                float sn, cs; sincosf(fs * inv, &sn, &cs);
                w2 = (u32)f2bf((v1.x * cs - v1.y * sn) * scale) |
                     ((u32)f2bf((v1.x * sn + v1.y * cs) * scale) << 16);
            }
            {
                const float inv = exp2f((float)((hd0 >> 1) + 3) * -0.4152410118609203f);
                float sn, cs; sincosf(fs * inv, &sn, &cs);
                w3 = (u32)f2bf((v1.z * cs - v1.w * sn) * scale) |
                     ((u32)f2bf((v1.z * sn + v1.w * cs) * scale) << 16);
            }
            uint4 ov; ov.x = w0; ov.y = w1; ov.z = w2; ov.w = w3;
            *(uint4*)&outp[((size_t)(bidx * HH + h) * SS + s) * HDD + hd0] = ov;
        }
    } else {
        float (*Ts)[64] = (float(*)[64])sm;
        #pragma unroll
        for (int fm = 0; fm < 2; fm++)
            #pragma unroll
            for (int fn = 0; fn < 4; fn++)
                *(float4*)&Ts[wc * 64 + fn * 16 + li][wr * 32 + fm * 16 + quad * 4] =
                    make_float4(acc[fm][fn][0], acc[fm][fn][1],
                                acc[fm][fn][2], acc[fm][fn][3]);
        __syncthreads();
        #pragma unroll
        for (int i = 0; i < 4; i++) {
            const int c = tid + 256 * i;     // 0..1023
            const int nr = c >> 3;           // 0..127
            const int mc = c & 7;            // 0..7
            const int n = n0 + nr;
            const int h = n >> 6, hd = n & 63;
            const float4 v0 = *(const float4*)&Ts[nr][mc * 8];
            const float4 v1 = *(const float4*)&Ts[nr][mc * 8 + 4];
            uint4 ov;
            ov.x = (u32)f2bf(v0.x) | ((u32)f2bf(v0.y) << 16);
            ov.y = (u32)f2bf(v0.z) | ((u32)f2bf(v0.w) << 16);
            ov.z = (u32)f2bf(v1.x) | ((u32)f2bf(v1.y) << 16);
            ov.w = (u32)f2bf(v1.z) | ((u32)f2bf(v1.w) << 16);
            *(uint4*)&outp[((size_t)(bidx * HH + h) * HDD + hd) * SS + s0 + mc * 8] = ov;
        }
    }
}

// ---------------- MFMA flash attention: 8 waves / 512 threads, shared K/V --------------
// Each wave owns one 16-q-row strip: rows q0 + 16*w + (quad*4+r). Waves 0-3: ntA
// tiles; waves 4-7: ntA+1. Diag mask row base = 16*(w&3) (derivation in R23 notes).
__global__ __launch_bounds__(512) void attn_mfma(
    const u16* __restrict__ Qb, const u16* __restrict__ Kb,
    const u16* __restrict__ Vt, u16* __restrict__ ctxb)
{
    __shared__ u16 Ks[64][72];      // [key][d]
    __shared__ u16 Vs[64][72];      // [d][key]  (from V^T)
    __shared__ u16 Ps[8][16][72];   // per-wave [q][key]
    const int tid = threadIdx.x;
    const int lane = tid & 63;
    const int w = tid >> 6;         // 0..7
    const int li = lane & 15;
    const int quad = lane >> 4;
    const int bh = blockIdx.y;
    const int q0 = (gridDim.x - 1 - (int)blockIdx.x) * 128;   // heavy blocks first

    bf16x8 aQ0, aQ1;
    {
        const u16* qg = Qb + ((size_t)bh * SS + q0 + 16 * w + li) * HDD + quad * 8;
        aQ0 = *(const bf16x8*)qg;
        aQ1 = *(const bf16x8*)(qg + 32);
    }

    f32x4 O[4] = {};
    float m_r[4] = {-1e30f, -1e30f, -1e30f, -1e30f};
    float l_r[4] = {};

    const int ntA = (q0 >> 6) + 1;
    const int ntw = ntA + (w >> 2);      // this wave's tile count
    const int ntB = ntA + 1;             // loop bound (all waves barrier together)
    const int krow = tid >> 3;           // 0..63
    const int kch = (tid & 7) * 8;       // 0..56
    const int mrow = 16 * (w & 3);       // diag mask row base

    for (int jt = 0; jt < ntB; jt++) {
        const int j0 = jt << 6;
        const uint4 kv = *(const uint4*)(Kb + ((size_t)bh * SS + j0 + krow) * HDD + kch);
        const uint4 vv = *(const uint4*)(Vt + ((size_t)bh * HDD + krow) * SS + j0 + kch);
        __syncthreads();
        *(uint4*)&Ks[krow][kch] = kv;
        *(uint4*)&Vs[krow][kch] = vv;
        __syncthreads();

        if (jt < ntw) {
            const bool diag = (jt == ntw - 1);
            f32x4 S[4];
            #pragma unroll
            for (int t = 0; t < 4; t++) {
                const bf16x8 b0 = *(const bf16x8*)&Ks[16 * t + li][quad * 8];
                const bf16x8 b1 = *(const bf16x8*)&Ks[16 * t + li][32 + quad * 8];
                f32x4 a2 = {};
                a2 = __builtin_amdgcn_mfma_f32_16x16x32_bf16(aQ0, b0, a2, 0, 0, 0);
                a2 = __builtin_amdgcn_mfma_f32_16x16x32_bf16(aQ1, b1, a2, 0, 0, 0);
                S[t] = a2;
            }
            if (diag) {
                #pragma unroll
                for (int t = 0; t < 4; t++)
                    #pragma unroll
                    for (int r = 0; r < 4; r++)
                        if (16 * t + li > mrow + quad * 4 + r) S[t][r] = -1e30f;
            }
            float p[4][4];
            #pragma unroll
            for (int r = 0; r < 4; r++) {
                float mt = fmaxf(fmaxf(S[0][r], S[1][r]), fmaxf(S[2][r], S[3][r]));
                #pragma unroll
                for (int off = 1; off < 16; off <<= 1)
                    mt = fmaxf(mt, __shfl_xor(mt, off));
                const float mnew = fmaxf(m_r[r], mt);
                const float alpha = __expf(m_r[r] - mnew);
                float ls = 0.f;
                #pragma unroll
                for (int t = 0; t < 4; t++) {
                    p[r][t] = __expf(S[t][r] - mnew);
                    ls += p[r][t];
                }
                #pragma unroll
                for (int off = 1; off < 16; off <<= 1)
                    ls += __shfl_xor(ls, off);
                l_r[r] = l_r[r] * alpha + ls;
                m_r[r] = mnew;
                #pragma unroll
                for (int t2 = 0; t2 < 4; t2++) O[t2][r] *= alpha;
            }
            #pragma unroll
            for (int r = 0; r < 4; r++)
                #pragma unroll
                for (int t = 0; t < 4; t++)
                    Ps[w][quad * 4 + r][16 * t + li] = f2bf(p[r][t]);
            const bf16x8 aP0 = *(const bf16x8*)&Ps[w][li][quad * 8];
            const bf16x8 aP1 = *(const bf16x8*)&Ps[w][li][32 + quad * 8];
            #pragma unroll
            for (int t2 = 0; t2 < 4; t2++) {
                const bf16x8 b0 = *(const bf16x8*)&Vs[16 * t2 + li][quad * 8];
                const bf16x8 b1 = *(const bf16x8*)&Vs[16 * t2 + li][32 + quad * 8];
                O[t2] = __builtin_amdgcn_mfma_f32_16x16x32_bf16(aP0, b0, O[t2], 0, 0, 0);
                O[t2] = __builtin_amdgcn_mfma_f32_16x16x32_bf16(aP1, b1, O[t2], 0, 0, 0);
            }
        }
    }

    const int b = bh >> 4, h = bh & 15;
    #pragma unroll
    for (int r = 0; r < 4; r++) {
        const float inv = 1.f / l_r[r];
        const int row = q0 + 16 * w + quad * 4 + r;
        #pragma unroll
        for (int t2 = 0; t2 < 4; t2++)
            ctxb[((size_t)b * SS + row) * DD + h * HDD + 16 * t2 + li] = f2bf(O[t2][r] * inv);
    }
}

// ---------------- output GEMM (R22 verbatim): 64x128 tile, gll16 staging ---------------
__global__ __launch_bounds__(256) void gemm_out_mfma(
    const u16* __restrict__ Ab, const u16* __restrict__ WoT, float* __restrict__ out)
{
    __shared__ __align__(16) u16 sm[12288];   // 24KB: 2 bufs x (A 4KB + B 8KB)
    const int tid = threadIdx.x;
    const int lane = tid & 63;
    const int w = tid >> 6;
    const int li = lane & 15, quad = lane >> 4;
    const int wr = w >> 1, wc = w & 1;
    const int n0 = blockIdx.x * 128;
    const int m0 = blockIdx.y * 64;

    const int arow = tid >> 2;
    const int acol = (tid & 3) * 8;
    const int wbase = (tid >> 6) * 1024;

    auto stage = [&](int t, int buf) {
        char* base = (char*)(sm + buf * 6144);
        const int k0 = t * 32;
        gll16(Ab + (size_t)(m0 + arow) * DD + k0 + acol, base + wbase);
        #pragma unroll
        for (int rr = 0; rr < 2; rr++)
            gll16(WoT + (size_t)(n0 + rr * 64 + arow) * DD + k0 + acol,
                  base + 4096 + rr * 4096 + wbase);
    };

    f32x4 acc[2][4] = {};
    stage(0, 0);
    __syncthreads();
    for (int t = 0; t < 32; t++) {
        const int buf = t & 1;
        if (t < 31) stage(t + 1, buf ^ 1);
        const u16* tA = sm + buf * 6144;
        const u16* tB = tA + 2048;
        bf16x8 a[2], b[4];
        #pragma unroll
        for (int f = 0; f < 2; f++)
            a[f] = *(const bf16x8*)(tA + (wr * 32 + f * 16 + li) * 32 + quad * 8);
        #pragma unroll
        for (int f = 0; f < 4; f++)
            b[f] = *(const bf16x8*)(tB + (wc * 64 + f * 16 + li) * 32 + quad * 8);
        #pragma unroll
        for (int fm = 0; fm < 2; fm++)
            #pragma unroll
            for (int fn = 0; fn < 4; fn++)
                acc[fm][fn] = __builtin_amdgcn_mfma_f32_16x16x32_bf16(
                    a[fm], b[fn], acc[fm][fn], 0, 0, 0);
        __syncthreads();
    }

    #pragma unroll
    for (int fm = 0; fm < 2; fm++)
        #pragma unroll
        for (int r = 0; r < 4; r++) {
            const size_t mg = (size_t)(m0 + wr * 32 + fm * 16 + quad * 4 + r) * DD;
            #pragma unroll
            for (int fn = 0; fn < 4; fn++)
                out[mg + n0 + wc * 64 + fn * 16 + li] = acc[fm][fn][r];
        }
}

extern "C" void kernel_launch(void* const* d_in, const int* in_sizes, int n_in,
                              void* d_out, int out_size, void* d_ws, size_t ws_size,
                              hipStream_t stream) {
    const float* x  = (const float*)d_in[0];
    const float* Wq = (const float*)d_in[1];
    const float* Wk = (const float*)d_in[2];
    const float* Wv = (const float*)d_in[3];
    const float* Wo = (const float*)d_in[4];
    float* out = (float*)d_out;

    u16* ws16 = (u16*)d_ws;
    const size_t E = 4194304;                 // B*H*S*HD elems
    const size_t M = 1048576;                 // D*D elems
    u16* QKVb = ws16;                         // [0,3E): Qb|Kb|Vt contiguous
    u16* Qb   = QKVb;
    u16* Kb   = QKVb + E;
    u16* Vt   = QKVb + 2 * E;
    u16* Xb   = ws16 + 3 * E;                 // [3E,4E), dead after QKV GEMM
    u16* ctxb = Xb;                           // reuse after QKV
    u16* WTall = ws16 + 4 * E;                // [4E,4E+3M): WqT|WkT|WvT contiguous
    u16* WoT  = WTall + 3 * M;                // [4E+3M, 4E+4M)  => 40 MiB total

    hipLaunchKernelGGL(cvt_x, dim3(1024), dim3(256), 0, stream, x, Xb);
    hipLaunchKernelGGL(trans_w, dim3(32, 32), dim3(256), 0, stream, Wq, WTall);
    hipLaunchKernelGGL(trans_w, dim3(32, 32), dim3(256), 0, stream, Wk, WTall + M);
    hipLaunchKernelGGL(trans_w, dim3(32, 32), dim3(256), 0, stream, Wv, WTall + 2 * M);
    hipLaunchKernelGGL(trans_w, dim3(32, 32), dim3(256), 0, stream, Wo, WoT);
    hipLaunchKernelGGL(gemm_qkv, dim3(24, 64), dim3(256), 0, stream, Xb, WTall, QKVb);
    hipLaunchKernelGGL(attn_mfma, dim3(SS / 128, BB * HH), dim3(512), 0, stream,
                       Qb, Kb, Vt, ctxb);
    hipLaunchKernelGGL(gemm_out_mfma, dim3(8, 64), dim3(256), 0, stream, ctxb, WoT, out);
}